// Round 12
// baseline (185.680 us; speedup 1.0000x reference)
//
#include <hip/hip_runtime.h>

typedef __attribute__((ext_vector_type(8))) short          bf16x8;
typedef __attribute__((ext_vector_type(8))) unsigned short u16x8;
typedef __attribute__((ext_vector_type(4))) unsigned short u16x4;
typedef __attribute__((ext_vector_type(4))) float          f32x4;
typedef __attribute__((ext_vector_type(4))) unsigned int   u32x4;

union U8 { u16x8 u; bf16x8 b; u32x4 w; };
union U4 { u16x4 u; unsigned w[2]; };

__device__ __forceinline__ unsigned short f2bf(float f){
  unsigned u = __float_as_uint(f);
  return (unsigned short)((u + 0x7fffu + ((u >> 16) & 1u)) >> 16);
}
// pack two floats to bf16x2 (round-half-up): lo->low16, hi->high16. exact 0 preserved.
__device__ __forceinline__ unsigned pack_bf16(float lo, float hi){
  unsigned a = __float_as_uint(hi) + 0x8000u;
  unsigned b = __float_as_uint(lo) + 0x8000u;
  return __builtin_amdgcn_perm(a, b, 0x07060302u);
}

#define NN  1024
#define FIN 256
#define NH  8
#define FO  64

// ---------------------------------------------------------------------------
// Stage 0: wfrag = w in MFMA-B-frag layout; Abits = bit-packed A (4-way MLP);
//          out = bias*mz (pre-init for head-merge atomics).
// ---------------------------------------------------------------------------
__global__ __launch_bounds__(256) void stage0(
    const float* __restrict__ w, const int* __restrict__ A,
    const float* __restrict__ bias, const float* __restrict__ mz,
    unsigned short* __restrict__ wfrag, unsigned long long* __restrict__ Abits,
    float* __restrict__ out)
{
  const int tid = blockIdx.x * 256 + threadIdx.x;    // 262144 threads
  if (tid < 16384){
    const int lane = tid & 63, ss = (tid >> 6) & 3, kc = (tid >> 8) & 7, h = tid >> 11;
    const int o = 16 * ss + (lane & 15);
    const int f = kc * 32 + (lane >> 4) * 8;
    u16x8 r;
    #pragma unroll
    for (int j = 0; j < 8; j++) r[j] = f2bf(w[(h * FIN + f + j) * FO + o]);
    *(u16x8*)(wfrag + tid * 8) = r;
  }
  #pragma unroll
  for (int k = 0; k < 2; k++){                       // out = bias*mz
    const int i = tid + k * 262144;
    out[i] = bias[i & 63] * mz[i >> 6];
  }
  // adjacency bit-pack: each wave does 256 elems/iter via 4 independent loads
  const int wid = tid >> 6, lane = threadIdx.x & 63;
  #pragma unroll
  for (int g = 0; g < 8; g++){
    const int base = g * 1048576 + wid * 256;
    const unsigned long long m0 = __ballot(A[base + lane] > 0);
    const unsigned long long m1 = __ballot(A[base + 64 + lane] > 0);
    const unsigned long long m2 = __ballot(A[base + 128 + lane] > 0);
    const unsigned long long m3 = __ballot(A[base + 192 + lane] > 0);
    if (lane == 0){
      Abits[(base >> 6) + 0] = m0;
      Abits[(base >> 6) + 1] = m1;
      Abits[(base >> 6) + 2] = m2;
      Abits[(base >> 6) + 3] = m3;
    }
  }
}

// ---------------------------------------------------------------------------
// Stage A: recx built in LDS per 16-row tile; h = recx @ w (MFMA);
// panel stores hT[b,h,mtile,o,32] + exp tables e^s, e^.2s, e^d, e^.2d.
// grid (64 tiles(16 rows), 8 b) = 512 blocks, block 512 (8 waves = 8 heads).
// ---------------------------------------------------------------------------
__global__ __launch_bounds__(512, 4) void stageA(
    const float* __restrict__ x, const float* __restrict__ e_at,
    const float* __restrict__ Np, const unsigned short* __restrict__ wfrag,
    const float* __restrict__ a_src, const float* __restrict__ a_dst,
    unsigned short* __restrict__ hT,
    float* __restrict__ exps, float* __restrict__ exps2,
    float* __restrict__ expd, float* __restrict__ expd2)
{
  __shared__ unsigned short rex[16 * 264];   // 16 rows x 256 f, pad 264
  const int t = threadIdx.x;
  const int n0 = blockIdx.x * 16, b = blockIdx.y;

  {                                          // cooperative recx tile build
    const int row = t >> 5, f0 = (t & 31) * 8;
    const int nrow = n0 + row;
    const float* ep = e_at + (b * NN + nrow) * FIN + f0;
    const float* qp = Np + nrow * FIN + f0;
    const float* xp = x + b * FIN + f0;
    f32x4 e0 = *(const f32x4*)ep, e1 = *(const f32x4*)(ep + 4);
    f32x4 q0 = *(const f32x4*)qp, q1 = *(const f32x4*)(qp + 4);
    f32x4 x0 = *(const f32x4*)xp, x1 = *(const f32x4*)(xp + 4);
    u16x8 r;
    #pragma unroll
    for (int j = 0; j < 4; j++){
      r[j]     = f2bf(e0[j] * q0[j] * x0[j]);
      r[j + 4] = f2bf(e1[j] * q1[j] * x1[j]);
    }
    *(u16x8*)(rex + row * 264 + f0) = r;
  }
  __syncthreads();

  const int h = t >> 6, lane = t & 63, quad = lane >> 4, l15 = lane & 15;
  const unsigned short* wf = wfrag + h * 16384 + lane * 8;

  f32x4 acc[4] = {};
  #pragma unroll
  for (int kc = 0; kc < 8; kc++){
    U8 a0, bf[4];
    a0.u = *(const u16x8*)(rex + l15 * 264 + kc * 32 + quad * 8);
    #pragma unroll
    for (int ss = 0; ss < 4; ss++) bf[ss].u = *(const u16x8*)(wf + (kc * 4 + ss) * 512);
    #pragma unroll
    for (int ss = 0; ss < 4; ss++)
      acc[ss] = __builtin_amdgcn_mfma_f32_16x16x32_bf16(a0.b, bf[ss].b, acc[ss], 0, 0, 0);
  }

  // panel store: [b,h,mtile,o(64),m(32)], C/D row(n)=quad*4+i, col(o)=16ss+l15
  {
    const int mtile = blockIdx.x >> 1, moff = (blockIdx.x & 1) * 16;
    unsigned short* pan = hT + (size_t)(((b * NH + h) * 32 + mtile) * 64) * 32;
    #pragma unroll
    for (int ss = 0; ss < 4; ss++){
      U4 v;
      v.w[0] = pack_bf16(acc[ss][0], acc[ss][1]);
      v.w[1] = pack_bf16(acc[ss][2], acc[ss][3]);
      *(u16x4*)(pan + (16 * ss + l15) * 32 + moff + quad * 4) = v.u;
    }
  }

  // s/d reductions -> exp tables
  float as4[4], ad4[4];
  #pragma unroll
  for (int ss = 0; ss < 4; ss++){
    as4[ss] = a_src[h * FO + 16 * ss + l15];
    ad4[ss] = a_dst[h * FO + 16 * ss + l15];
  }
  #pragma unroll
  for (int i = 0; i < 4; i++){
    float ps = 0.f, pd = 0.f;
    #pragma unroll
    for (int ss = 0; ss < 4; ss++){ ps += acc[ss][i] * as4[ss]; pd += acc[ss][i] * ad4[ss]; }
    #pragma unroll
    for (int off = 1; off < 16; off <<= 1){
      ps += __shfl_xor(ps, off);
      pd += __shfl_xor(pd, off);
    }
    if (l15 == 0){
      const int idx = (b * NH + h) * NN + n0 + quad * 4 + i;
      exps [idx] = __expf(ps);
      exps2[idx] = __expf(0.2f * ps);
      expd [idx] = __expf(pd);
      expd2[idx] = __expf(0.2f * pd);
    }
  }
}

// ---------------------------------------------------------------------------
// Stage B: fused masked-softmax aggregation (R11 + depth-2 prefetch +
// ones-MFMA row-sum + LDS oacc merge).  XCD swizzle: 32 row-tile blocks of a
// (b,head-pair) panel share an XCD -> panel L2-resident (proven R11: FETCH 5x
// down).  grid 1024 linear, block 512 (8 waves = 2h x 2rg x 2mh).
// ---------------------------------------------------------------------------
#define BCHUNK(C, PAN)                                                          \
  {                                                                             \
    const int c_ = (C);                                                         \
    const unsigned am_ = maskp[c_] >> (quad * 8);                               \
    float pv_[8];                                                               \
    _Pragma("unroll")                                                           \
    for (int g2_ = 0; g2_ < 2; g2_++){                                          \
      f32x4 dv_ = *(const f32x4*)(edh + c_ * 32 + g2_ * 4);                     \
      f32x4 gv_ = *(const f32x4*)(e2h + c_ * 32 + g2_ * 4);                     \
      _Pragma("unroll")                                                         \
      for (int jj_ = 0; jj_ < 4; jj_++){                                        \
        const float e_ = fmaxf(Es * dv_[jj_], Es2 * gv_[jj_]);                  \
        pv_[g2_ * 4 + jj_] = (am_ & (1u << (g2_ * 4 + jj_))) ? e_ : 0.f;        \
      }                                                                         \
    }                                                                           \
    U8 pk_;                                                                     \
    _Pragma("unroll")                                                           \
    for (int r_ = 0; r_ < 4; r_++) pk_.w[r_] = pack_bf16(pv_[2 * r_], pv_[2 * r_ + 1]); \
    _Pragma("unroll")                                                           \
    for (int ss_ = 0; ss_ < 4; ss_++)                                           \
      acc[ss_] = __builtin_amdgcn_mfma_f32_16x16x32_bf16(pk_.b, PAN[ss_].b, acc[ss_], 0, 0, 0); \
    accs = __builtin_amdgcn_mfma_f32_16x16x32_bf16(pk_.b, ones.b, accs, 0, 0, 0); \
  }

__global__ __launch_bounds__(512, 8) void stageB(
    const unsigned* __restrict__ Aw,
    const unsigned short* __restrict__ hT,
    const float* __restrict__ exps, const float* __restrict__ exps2,
    const float* __restrict__ expd, const float* __restrict__ expd2,
    const float* __restrict__ mz, float* __restrict__ out)
{
  __shared__ float ed_l[2 * NN];         // 8 KB (2 heads)
  __shared__ float e2_l[2 * NN];         // 8 KB
  __shared__ unsigned mask_l[32 * 33];   // 4.2 KB
  __shared__ float l_l[64];              // (hl,rg) x 16 rows
  __shared__ float oacc[32 * 65];        // 8.3 KB block-level merge
  const int t = threadIdx.x;

  // ---- XCD swizzle: id = 8*(pp*32 + j) + xcd ;  panel p = pp*8+xcd ----
  const int id  = blockIdx.x;
  const int xcd = id & 7;
  const int rest = id >> 3;
  const int j   = rest & 31;             // row-tile 0..31
  const int p   = (rest >> 5) * 8 + xcd; // panel 0..31
  const int n0  = j * 32;
  const int hq  = p & 3;                 // head-pair 0..3
  const int b   = p >> 2;                // batch 0..7

  const int w = t >> 6, lane = t & 63, quad = lane >> 4, l15 = lane & 15;
  const int hl = w & 1, rg = (w >> 1) & 1, mh = w >> 2;
  const int h = hq * 2 + hl;

  if (t < 64) l_l[t] = 0.f;
  for (int i = t; i < 32 * 65; i += 512) oacc[i] = 0.f;
  {                                      // exp-table preload (coalesced)
    const float* s1 = expd  + (b * NH + hq * 2) * NN;
    const float* s2 = expd2 + (b * NH + hq * 2) * NN;
    *(f32x4*)(ed_l + t * 4) = *(const f32x4*)(s1 + t * 4);
    *(f32x4*)(e2_l + t * 4) = *(const f32x4*)(s2 + t * 4);
  }
  #pragma unroll
  for (int k = 0; k < 2; k++){
    const int i = t + k * 512;
    mask_l[(i >> 5) * 33 + (i & 31)] = Aw[(b * NN + n0 + (i >> 5)) * 32 + (i & 31)];
  }
  __syncthreads();

  const int hb = (b * NH + h) * NN;
  const float Es  = exps [hb + n0 + rg * 16 + l15];
  const float Es2 = exps2[hb + n0 + rg * 16 + l15];
  const unsigned short* pb = hT + (size_t)(b * NH + h) * 65536 + l15 * 32 + quad * 8;
  const float* edh = ed_l + hl * NN + quad * 8;
  const float* e2h = e2_l + hl * NN + quad * 8;
  const unsigned* maskp = mask_l + (rg * 16 + l15) * 33;
  const int c0 = mh * 16;

  U8 ones;                               // all-ones B: row sums on idle MFMA pipe
  #pragma unroll
  for (int jj = 0; jj < 8; jj++) ones.u[jj] = 0x3F80;

  U8 pan0[4], pan1[4];                   // depth-2: two named buffers, no copies
  #pragma unroll
  for (int ss = 0; ss < 4; ss++){
    pan0[ss].u = *(const u16x8*)(pb + (size_t)c0 * 2048 + ss * 512);
    pan1[ss].u = *(const u16x8*)(pb + (size_t)(c0 + 1) * 2048 + ss * 512);
  }

  f32x4 acc[4] = {}, accs = {};

  for (int cc = 0; cc < 16; cc += 2){
    BCHUNK(c0 + cc, pan0)
    if (cc + 2 < 16){
      #pragma unroll
      for (int ss = 0; ss < 4; ss++)
        pan0[ss].u = *(const u16x8*)(pb + (size_t)(c0 + cc + 2) * 2048 + ss * 512);
    }
    BCHUNK(c0 + cc + 1, pan1)
    if (cc + 3 < 16){
      #pragma unroll
      for (int ss = 0; ss < 4; ss++)
        pan1[ss].u = *(const u16x8*)(pb + (size_t)(c0 + cc + 3) * 2048 + ss * 512);
    }
  }

  // accs[i] = partial row sum for row rg*16+quad*4+i over this mh's 512 m
  if (l15 == 0){
    #pragma unroll
    for (int i = 0; i < 4; i++)
      atomicAdd(&l_l[(w & 3) * 16 + quad * 4 + i], accs[i]);
  }
  __syncthreads();

  // normalize (1/8 folded) * mz; merge 8 waves in LDS oacc
  const float* mzp = mz + b * NN + n0 + rg * 16;
  #pragma unroll
  for (int i = 0; i < 4; i++){
    const int r16 = quad * 4 + i;
    const float invm = (0.125f / l_l[(w & 3) * 16 + r16]) * mzp[r16];
    #pragma unroll
    for (int ss = 0; ss < 4; ss++)
      atomicAdd(&oacc[(rg * 16 + r16) * 65 + ss * 16 + l15], acc[ss][i] * invm);
  }
  __syncthreads();

  // one global atomic per out element per block (4-way hq merge)
  for (int i = t; i < 2048; i += 512){
    const int r = i >> 6, o = i & 63;
    atomicAdd(out + (size_t)(b * NN + n0 + r) * FO + o, oacc[r * 65 + o]);
  }
}

extern "C" void kernel_launch(void* const* d_in, const int* in_sizes, int n_in,
                              void* d_out, int out_size, void* d_ws, size_t ws_size,
                              hipStream_t stream)
{
  (void)in_sizes; (void)n_in; (void)out_size; (void)ws_size;
  const float* x    = (const float*)d_in[0];
  const int*   A    = (const int*)d_in[1];
  const float* mz   = (const float*)d_in[2];
  const float* e_at = (const float*)d_in[4];
  const float* Np   = (const float*)d_in[5];
  const float* w    = (const float*)d_in[6];
  const float* asrc = (const float*)d_in[7];
  const float* adst = (const float*)d_in[8];
  const float* bias = (const float*)d_in[9];
  float* out = (float*)d_out;

  char* ws = (char*)d_ws;
  unsigned short* wfrag = (unsigned short*)ws;                     // 256 KB
  unsigned short* hT    = (unsigned short*)(ws + 262144);          // 8 MB
  float* exps  = (float*)(ws + 8650752);                           // 256 KB
  float* exps2 = (float*)(ws + 8912896);                           // 256 KB
  float* expd  = (float*)(ws + 9175040);                           // 256 KB
  float* expd2 = (float*)(ws + 9437184);                           // 256 KB
  unsigned long long* Abits = (unsigned long long*)(ws + 9699328); // 1 MB

  stage0<<<dim3(1024), dim3(256), 0, stream>>>(w, A, bias, mz, wfrag, Abits, out);
  stageA<<<dim3(64, 8), dim3(512), 0, stream>>>(x, e_at, Np, wfrag, asrc, adst,
                                                hT, exps, exps2, expd, expd2);
  stageB<<<dim3(1024), dim3(512), 0, stream>>>((const unsigned*)Abits, hT,
                                               exps, exps2, expd, expd2,
                                               mz, out);
}